// Round 22
// baseline (539.679 us; speedup 1.0000x reference)
//
#include <hip/hip_runtime.h>

// Cvxpy_81174881894666: batched dual ascent (R22: mega-asm, fast cross-lane)
//   per batch b: 100 iters of
//     z = a^T lam;  y = sigmoid(-(c+z));  g = a y + b;  lam = max(lam+0.05 g, 0)
//   out: y = sigmoid(-(c + a^T lam_final)) [2048,256] f32, status int32 zeros.
//
// R21 post-mortem: AGPR-tax model FALSIFIED (tax-free asm = 511us > R11 454).
// Binding cost = serial critical path: 16 ds_swizzle (~30cy) + 3 LDS round
// trips + 2 barriers ~ 1360cy/block-iter. R22 keeps the asm register control,
// shortens the path: lambda via v_readlane->SGPR broadcast (no LDS), reduce
// via permlane32/16_swap + DPP (R11's verified tree; 1 swizzle left), DS ops
// 30->7/iter. s_nop hazard pads for DPP/readlane/TRANS consumers.

#define BB 2048
#define MM 128
#define NN 256

__global__ __launch_bounds__(512, 2) void cvx_dual_ascent(
    const float* __restrict__ A,
    const float* __restrict__ Bv,
    const float* __restrict__ C,
    float* __restrict__ out)
{
    const int bi  = blockIdx.x;
    const int tid = threadIdx.x;
    const int w   = tid >> 6;          // wave 0..7 -> rows [16w,16w+16)
    const int l   = tid & 63;
    const int c   = tid >> 1;          // P2/out column (2 threads per col)
    const int myrow = (l >> 2) & 15;   // row owned after reduce (R11 map)

    __shared__ float zp_s[8][260];     // z partials [wave][col]
    __shared__ float y_s[NN];

    const float* Ab = A + (size_t)bi * (MM * NN);
    unsigned long long a0  = (unsigned long long)(Ab + (16*w + 0)  * NN + 4*l);
    unsigned long long a4  = (unsigned long long)(Ab + (16*w + 4)  * NN + 4*l);
    unsigned long long a8  = (unsigned long long)(Ab + (16*w + 8)  * NN + 4*l);
    unsigned long long a12 = (unsigned long long)(Ab + (16*w + 12) * NN + 4*l);
    unsigned zpw   = (unsigned)(size_t)&zp_s[w][4*l];
    unsigned zprd  = (unsigned)(size_t)&zp_s[(tid & 1) * 4][c];
    unsigned ysw   = (unsigned)(size_t)&y_s[c];
    unsigned ysr   = (unsigned)(size_t)&y_s[4*l];
    unsigned long long outa = (unsigned long long)(out + (size_t)bi * NN + c);
    float cr  = C[bi * NN + c];
    float sbv = 0.05f * Bv[bi * MM + 16*w + myrow];
    float lam = 0.f;
    int   cnt = 100;

    __syncthreads();

    asm volatile(
        // ---- A tile -> v[36:99] (row i, col j -> v(36+4i+j)); lam s80-95=0 ----
        "global_load_dwordx4 v[36:39], %[a0], off\n\t"
        "global_load_dwordx4 v[40:43], %[a0], off offset:1024\n\t"
        "global_load_dwordx4 v[44:47], %[a0], off offset:2048\n\t"
        "global_load_dwordx4 v[48:51], %[a0], off offset:3072\n\t"
        "global_load_dwordx4 v[52:55], %[a4], off\n\t"
        "global_load_dwordx4 v[56:59], %[a4], off offset:1024\n\t"
        "global_load_dwordx4 v[60:63], %[a4], off offset:2048\n\t"
        "global_load_dwordx4 v[64:67], %[a4], off offset:3072\n\t"
        "global_load_dwordx4 v[68:71], %[a8], off\n\t"
        "global_load_dwordx4 v[72:75], %[a8], off offset:1024\n\t"
        "global_load_dwordx4 v[76:79], %[a8], off offset:2048\n\t"
        "global_load_dwordx4 v[80:83], %[a8], off offset:3072\n\t"
        "global_load_dwordx4 v[84:87], %[a12], off\n\t"
        "global_load_dwordx4 v[88:91], %[a12], off offset:1024\n\t"
        "global_load_dwordx4 v[92:95], %[a12], off offset:2048\n\t"
        "global_load_dwordx4 v[96:99], %[a12], off offset:3072\n\t"
        "s_mov_b32 s80, 0\n\t"  "s_mov_b32 s81, 0\n\t"
        "s_mov_b32 s82, 0\n\t"  "s_mov_b32 s83, 0\n\t"
        "s_mov_b32 s84, 0\n\t"  "s_mov_b32 s85, 0\n\t"
        "s_mov_b32 s86, 0\n\t"  "s_mov_b32 s87, 0\n\t"
        "s_mov_b32 s88, 0\n\t"  "s_mov_b32 s89, 0\n\t"
        "s_mov_b32 s90, 0\n\t"  "s_mov_b32 s91, 0\n\t"
        "s_mov_b32 s92, 0\n\t"  "s_mov_b32 s93, 0\n\t"
        "s_mov_b32 s94, 0\n\t"  "s_mov_b32 s95, 0\n\t"
        "s_waitcnt vmcnt(0)\n\t"
        ".LTOP%=:\n\t"
        // ---- P1: zp[4] = sum_i A[i][j] * lam(s80+i); acc v116-119 ----
        "v_mul_f32 v116, s80, v36\n\t"
        "v_mul_f32 v117, s80, v37\n\t"
        "v_mul_f32 v118, s80, v38\n\t"
        "v_mul_f32 v119, s80, v39\n\t"
        "v_fmac_f32 v116, s81, v40\n\t"
        "v_fmac_f32 v117, s81, v41\n\t"
        "v_fmac_f32 v118, s81, v42\n\t"
        "v_fmac_f32 v119, s81, v43\n\t"
        "v_fmac_f32 v116, s82, v44\n\t"
        "v_fmac_f32 v117, s82, v45\n\t"
        "v_fmac_f32 v118, s82, v46\n\t"
        "v_fmac_f32 v119, s82, v47\n\t"
        "v_fmac_f32 v116, s83, v48\n\t"
        "v_fmac_f32 v117, s83, v49\n\t"
        "v_fmac_f32 v118, s83, v50\n\t"
        "v_fmac_f32 v119, s83, v51\n\t"
        "v_fmac_f32 v116, s84, v52\n\t"
        "v_fmac_f32 v117, s84, v53\n\t"
        "v_fmac_f32 v118, s84, v54\n\t"
        "v_fmac_f32 v119, s84, v55\n\t"
        "v_fmac_f32 v116, s85, v56\n\t"
        "v_fmac_f32 v117, s85, v57\n\t"
        "v_fmac_f32 v118, s85, v58\n\t"
        "v_fmac_f32 v119, s85, v59\n\t"
        "v_fmac_f32 v116, s86, v60\n\t"
        "v_fmac_f32 v117, s86, v61\n\t"
        "v_fmac_f32 v118, s86, v62\n\t"
        "v_fmac_f32 v119, s86, v63\n\t"
        "v_fmac_f32 v116, s87, v64\n\t"
        "v_fmac_f32 v117, s87, v65\n\t"
        "v_fmac_f32 v118, s87, v66\n\t"
        "v_fmac_f32 v119, s87, v67\n\t"
        "v_fmac_f32 v116, s88, v68\n\t"
        "v_fmac_f32 v117, s88, v69\n\t"
        "v_fmac_f32 v118, s88, v70\n\t"
        "v_fmac_f32 v119, s88, v71\n\t"
        "v_fmac_f32 v116, s89, v72\n\t"
        "v_fmac_f32 v117, s89, v73\n\t"
        "v_fmac_f32 v118, s89, v74\n\t"
        "v_fmac_f32 v119, s89, v75\n\t"
        "v_fmac_f32 v116, s90, v76\n\t"
        "v_fmac_f32 v117, s90, v77\n\t"
        "v_fmac_f32 v118, s90, v78\n\t"
        "v_fmac_f32 v119, s90, v79\n\t"
        "v_fmac_f32 v116, s91, v80\n\t"
        "v_fmac_f32 v117, s91, v81\n\t"
        "v_fmac_f32 v118, s91, v82\n\t"
        "v_fmac_f32 v119, s91, v83\n\t"
        "v_fmac_f32 v116, s92, v84\n\t"
        "v_fmac_f32 v117, s92, v85\n\t"
        "v_fmac_f32 v118, s92, v86\n\t"
        "v_fmac_f32 v119, s92, v87\n\t"
        "v_fmac_f32 v116, s93, v88\n\t"
        "v_fmac_f32 v117, s93, v89\n\t"
        "v_fmac_f32 v118, s93, v90\n\t"
        "v_fmac_f32 v119, s93, v91\n\t"
        "v_fmac_f32 v116, s94, v92\n\t"
        "v_fmac_f32 v117, s94, v93\n\t"
        "v_fmac_f32 v118, s94, v94\n\t"
        "v_fmac_f32 v119, s94, v95\n\t"
        "v_fmac_f32 v116, s95, v96\n\t"
        "v_fmac_f32 v117, s95, v97\n\t"
        "v_fmac_f32 v118, s95, v98\n\t"
        "v_fmac_f32 v119, s95, v99\n\t"
        "ds_write_b128 %[zpw], v[116:119]\n\t"
        "s_waitcnt lgkmcnt(0)\n\t"
        "s_barrier\n\t"
        // ---- P2: z over 8 waves + pair xor1 (DPP); sigmoid ----
        "ds_read_b32 v120, %[zprd]\n\t"
        "ds_read_b32 v121, %[zprd] offset:1040\n\t"
        "ds_read_b32 v122, %[zprd] offset:2080\n\t"
        "ds_read_b32 v123, %[zprd] offset:3120\n\t"
        "s_waitcnt lgkmcnt(0)\n\t"
        "v_add_f32 v120, v120, v121\n\t"
        "v_add_f32 v122, v122, v123\n\t"
        "v_add_f32 v120, v120, v122\n\t"
        "s_nop 1\n\t"
        "v_mov_b32_dpp v121, v120 quad_perm:[1,0,3,2] row_mask:0xf bank_mask:0xf\n\t"
        "v_add_f32 v120, v120, v121\n\t"
        "v_add_f32 v121, %[cr], v120\n\t"
        "v_mul_f32 v121, %[l2e], v121\n\t"
        "v_exp_f32 v121, v121\n\t"
        "s_nop 1\n\t"
        "v_add_f32 v121, 1.0, v121\n\t"
        "v_rcp_f32 v121, v121\n\t"
        "s_nop 1\n\t"
        "s_cmp_eq_u32 %[cnt], 0\n\t"
        "s_cbranch_scc1 .LEXIT%=\n\t"
        // ---- publish y ----
        "ds_write_b32 %[ysw], v121\n\t"
        "s_waitcnt lgkmcnt(0)\n\t"
        "s_barrier\n\t"
        // ---- P3: p[16] = A y (y4 v116-119; p v100-115) ----
        "ds_read_b128 v[116:119], %[ysr]\n\t"
        "s_waitcnt lgkmcnt(0)\n\t"
        "v_mul_f32 v100, v36, v116\n\t"
        "v_mul_f32 v101, v40, v116\n\t"
        "v_mul_f32 v102, v44, v116\n\t"
        "v_mul_f32 v103, v48, v116\n\t"
        "v_mul_f32 v104, v52, v116\n\t"
        "v_mul_f32 v105, v56, v116\n\t"
        "v_mul_f32 v106, v60, v116\n\t"
        "v_mul_f32 v107, v64, v116\n\t"
        "v_mul_f32 v108, v68, v116\n\t"
        "v_mul_f32 v109, v72, v116\n\t"
        "v_mul_f32 v110, v76, v116\n\t"
        "v_mul_f32 v111, v80, v116\n\t"
        "v_mul_f32 v112, v84, v116\n\t"
        "v_mul_f32 v113, v88, v116\n\t"
        "v_mul_f32 v114, v92, v116\n\t"
        "v_mul_f32 v115, v96, v116\n\t"
        "v_fmac_f32 v100, v37, v117\n\t"
        "v_fmac_f32 v101, v41, v117\n\t"
        "v_fmac_f32 v102, v45, v117\n\t"
        "v_fmac_f32 v103, v49, v117\n\t"
        "v_fmac_f32 v104, v53, v117\n\t"
        "v_fmac_f32 v105, v57, v117\n\t"
        "v_fmac_f32 v106, v61, v117\n\t"
        "v_fmac_f32 v107, v65, v117\n\t"
        "v_fmac_f32 v108, v69, v117\n\t"
        "v_fmac_f32 v109, v73, v117\n\t"
        "v_fmac_f32 v110, v77, v117\n\t"
        "v_fmac_f32 v111, v81, v117\n\t"
        "v_fmac_f32 v112, v85, v117\n\t"
        "v_fmac_f32 v113, v89, v117\n\t"
        "v_fmac_f32 v114, v93, v117\n\t"
        "v_fmac_f32 v115, v97, v117\n\t"
        "v_fmac_f32 v100, v38, v118\n\t"
        "v_fmac_f32 v101, v42, v118\n\t"
        "v_fmac_f32 v102, v46, v118\n\t"
        "v_fmac_f32 v103, v50, v118\n\t"
        "v_fmac_f32 v104, v54, v118\n\t"
        "v_fmac_f32 v105, v58, v118\n\t"
        "v_fmac_f32 v106, v62, v118\n\t"
        "v_fmac_f32 v107, v66, v118\n\t"
        "v_fmac_f32 v108, v70, v118\n\t"
        "v_fmac_f32 v109, v74, v118\n\t"
        "v_fmac_f32 v110, v78, v118\n\t"
        "v_fmac_f32 v111, v82, v118\n\t"
        "v_fmac_f32 v112, v86, v118\n\t"
        "v_fmac_f32 v113, v90, v118\n\t"
        "v_fmac_f32 v114, v94, v118\n\t"
        "v_fmac_f32 v115, v98, v118\n\t"
        "v_fmac_f32 v100, v39, v119\n\t"
        "v_fmac_f32 v101, v43, v119\n\t"
        "v_fmac_f32 v102, v47, v119\n\t"
        "v_fmac_f32 v103, v51, v119\n\t"
        "v_fmac_f32 v104, v55, v119\n\t"
        "v_fmac_f32 v105, v59, v119\n\t"
        "v_fmac_f32 v106, v63, v119\n\t"
        "v_fmac_f32 v107, v67, v119\n\t"
        "v_fmac_f32 v108, v71, v119\n\t"
        "v_fmac_f32 v109, v75, v119\n\t"
        "v_fmac_f32 v110, v79, v119\n\t"
        "v_fmac_f32 v111, v83, v119\n\t"
        "v_fmac_f32 v112, v87, v119\n\t"
        "v_fmac_f32 v113, v91, v119\n\t"
        "v_fmac_f32 v114, v95, v119\n\t"
        "v_fmac_f32 v115, v99, v119\n\t"
        // ---- reduce (R11 tree): swap32+add x8 -> swap16+add x4 ----
        "s_nop 1\n\t"
        "v_permlane32_swap_b32 v100, v108\n\t"
        "v_permlane32_swap_b32 v101, v109\n\t"
        "v_permlane32_swap_b32 v102, v110\n\t"
        "v_permlane32_swap_b32 v103, v111\n\t"
        "v_permlane32_swap_b32 v104, v112\n\t"
        "v_permlane32_swap_b32 v105, v113\n\t"
        "v_permlane32_swap_b32 v106, v114\n\t"
        "v_permlane32_swap_b32 v107, v115\n\t"
        "v_add_f32 v100, v100, v108\n\t"
        "v_add_f32 v101, v101, v109\n\t"
        "v_add_f32 v102, v102, v110\n\t"
        "v_add_f32 v103, v103, v111\n\t"
        "v_add_f32 v104, v104, v112\n\t"
        "v_add_f32 v105, v105, v113\n\t"
        "v_add_f32 v106, v106, v114\n\t"
        "v_add_f32 v107, v107, v115\n\t"
        "v_permlane16_swap_b32 v100, v104\n\t"
        "v_permlane16_swap_b32 v101, v105\n\t"
        "v_permlane16_swap_b32 v102, v106\n\t"
        "v_permlane16_swap_b32 v103, v107\n\t"
        "v_add_f32 v100, v100, v104\n\t"
        "v_add_f32 v101, v101, v105\n\t"
        "v_add_f32 v102, v102, v106\n\t"
        "v_add_f32 v103, v103, v107\n\t"
        // ---- round xor8 (cndmask + DPP row_ror:8) ----
        "v_cndmask_b32 v120, v100, v102, %[mb3]\n\t"
        "v_cndmask_b32 v121, v102, v100, %[mb3]\n\t"
        "v_cndmask_b32 v122, v101, v103, %[mb3]\n\t"
        "v_cndmask_b32 v123, v103, v101, %[mb3]\n\t"
        "s_nop 1\n\t"
        "v_mov_b32_dpp v124, v121 row_ror:8 row_mask:0xf bank_mask:0xf\n\t"
        "v_mov_b32_dpp v125, v123 row_ror:8 row_mask:0xf bank_mask:0xf\n\t"
        "v_add_f32 v100, v120, v124\n\t"
        "v_add_f32 v101, v122, v125\n\t"
        // ---- round xor4 (cndmask + ds_swizzle) ----
        "v_cndmask_b32 v120, v100, v101, %[mb2]\n\t"
        "v_cndmask_b32 v121, v101, v100, %[mb2]\n\t"
        "ds_swizzle_b32 v121, v121 offset:0x101F\n\t"
        "s_waitcnt lgkmcnt(0)\n\t"
        "v_add_f32 v100, v120, v121\n\t"
        // ---- butterflies xor2, xor1 (DPP quad_perm) ----
        "s_nop 1\n\t"
        "v_mov_b32_dpp v121, v100 quad_perm:[2,3,0,1] row_mask:0xf bank_mask:0xf\n\t"
        "v_add_f32 v100, v100, v121\n\t"
        "s_nop 1\n\t"
        "v_mov_b32_dpp v121, v100 quad_perm:[1,0,3,2] row_mask:0xf bank_mask:0xf\n\t"
        "v_add_f32 v100, v100, v121\n\t"
        // ---- lambda update + SGPR broadcast (lam[i] in lane 4i) ----
        "v_fmac_f32 %[lam], %[step], v100\n\t"
        "v_add_f32 %[lam], %[sb], %[lam]\n\t"
        "v_max_f32 %[lam], 0, %[lam]\n\t"
        "s_nop 1\n\t"
        "v_readlane_b32 s80, %[lam], 0\n\t"
        "v_readlane_b32 s81, %[lam], 4\n\t"
        "v_readlane_b32 s82, %[lam], 8\n\t"
        "v_readlane_b32 s83, %[lam], 12\n\t"
        "v_readlane_b32 s84, %[lam], 16\n\t"
        "v_readlane_b32 s85, %[lam], 20\n\t"
        "v_readlane_b32 s86, %[lam], 24\n\t"
        "v_readlane_b32 s87, %[lam], 28\n\t"
        "v_readlane_b32 s88, %[lam], 32\n\t"
        "v_readlane_b32 s89, %[lam], 36\n\t"
        "v_readlane_b32 s90, %[lam], 40\n\t"
        "v_readlane_b32 s91, %[lam], 44\n\t"
        "v_readlane_b32 s92, %[lam], 48\n\t"
        "v_readlane_b32 s93, %[lam], 52\n\t"
        "v_readlane_b32 s94, %[lam], 56\n\t"
        "v_readlane_b32 s95, %[lam], 60\n\t"
        "s_sub_u32 %[cnt], %[cnt], 1\n\t"
        "s_branch .LTOP%=\n\t"
        ".LEXIT%=:\n\t"
        "global_store_dword %[outa], v121, off\n\t"
        "s_waitcnt vmcnt(0)\n\t"
        : [lam] "+v"(lam), [cnt] "+s"(cnt)
        : [a0] "v"(a0), [a4] "v"(a4), [a8] "v"(a8), [a12] "v"(a12),
          [zpw] "v"(zpw), [zprd] "v"(zprd),
          [ysw] "v"(ysw), [ysr] "v"(ysr), [outa] "v"(outa),
          [cr] "v"(cr), [sb] "v"(sbv),
          [step] "s"(0.05f), [l2e] "s"(1.4426950408889634f),
          [mb3] "s"(0xFF00FF00FF00FF00ull), [mb2] "s"(0xF0F0F0F0F0F0F0F0ull)
        : "memory", "scc",
          "s80","s81","s82","s83","s84","s85","s86","s87",
          "s88","s89","s90","s91","s92","s93","s94","s95",
          "v36","v37","v38","v39","v40","v41","v42","v43","v44","v45",
          "v46","v47","v48","v49","v50","v51","v52","v53","v54","v55",
          "v56","v57","v58","v59","v60","v61","v62","v63","v64","v65",
          "v66","v67","v68","v69","v70","v71","v72","v73","v74","v75",
          "v76","v77","v78","v79","v80","v81","v82","v83","v84","v85",
          "v86","v87","v88","v89","v90","v91","v92","v93","v94","v95",
          "v96","v97","v98","v99","v100","v101","v102","v103","v104",
          "v105","v106","v107","v108","v109","v110","v111","v112","v113",
          "v114","v115","v116","v117","v118","v119","v120","v121","v122",
          "v123","v124","v125","v126","v127");

    if (tid == 0) out[(size_t)BB * NN + bi] = 0.0f;  // status[bi] = int32 0
}

extern "C" void kernel_launch(void* const* d_in, const int* in_sizes, int n_in,
                              void* d_out, int out_size, void* d_ws, size_t ws_size,
                              hipStream_t stream) {
    const float* A  = (const float*)d_in[0];  // [2048,128,256]
    const float* Bv = (const float*)d_in[1];  // [2048,128]
    const float* C  = (const float*)d_in[2];  // [2048,256]
    float* out = (float*)d_out;               // y [2048,256] f32 ++ status [2048]

    cvx_dual_ascent<<<dim3(BB), dim3(512), 0, stream>>>(A, Bv, C, out);
}